// Round 7
// baseline (56.186 us; speedup 1.0000x reference)
//
#include <hip/hip_runtime.h>

#define HW_   (512*512)         // 262144 pixels per image
#define NC    16
#define NPIX  (8*HW_)
#define NGRP  (NPIX/4)          // 524288 float4 groups
#define GPB4  (HW_/4)           // 65536 groups per image (2^16)
#define NBLK  1024              // 4 blocks/CU = 16 waves/CU (needs VGPR <= 128)
#define NTHR  256
#define NBUK  16

// ws layout (floats): [NBUK][48] partials; ws[NBUK*48] = block counter (int)
// stat s: 0..15 = p_sum[c], 16..31 = intersection[c], 32..47 = t_sum[c]

__device__ __forceinline__ float wred(float v) {
    v += __shfl_xor(v, 32, 64);
    v += __shfl_xor(v, 16, 64);
    v += __shfl_xor(v,  8, 64);
    v += __shfl_xor(v,  4, 64);
    v += __shfl_xor(v,  2, 64);
    v += __shfl_xor(v,  1, 64);
    return v;
}

__global__ __launch_bounds__(NTHR) void dice_main(
        const float* __restrict__ logits,
        const int*   __restrict__ targets,
        float*       __restrict__ ws,
        float*       __restrict__ out) {
    __shared__ float red[4][48];
    __shared__ float fin[48];
    __shared__ int   isLast;

    float psum[NC], inter[NC], tsum[NC];
    #pragma unroll
    for (int c = 0; c < NC; ++c) { psum[c] = 0.f; inter[c] = 0.f; tsum[c] = 0.f; }

    const int nthreads = NBLK * NTHR;
    for (int g = blockIdx.x * NTHR + threadIdx.x; g < NGRP; g += nthreads) {
        const int b  = g >> 16;        // g / GPB4
        const int s4 = g & (GPB4 - 1); // g % GPB4
        const float4* lp = reinterpret_cast<const float4*>(logits) + (size_t)b * (NC * GPB4) + s4;
        const int4 t = reinterpret_cast<const int4*>(targets)[(size_t)b * GPB4 + s4];

        float4 e[NC];
        float sx = 0.f, sy = 0.f, sz = 0.f, sw = 0.f;
        #pragma unroll
        for (int c = 0; c < NC; ++c) {
            float4 l = lp[(size_t)c * GPB4];
            e[c].x = __expf(l.x); e[c].y = __expf(l.y);
            e[c].z = __expf(l.z); e[c].w = __expf(l.w);
            sx += e[c].x; sy += e[c].y; sz += e[c].z; sw += e[c].w;
        }
        const float ix = __builtin_amdgcn_rcpf(sx);
        const float iy = __builtin_amdgcn_rcpf(sy);
        const float iz = __builtin_amdgcn_rcpf(sz);
        const float iw = __builtin_amdgcn_rcpf(sw);

        #pragma unroll
        for (int c = 0; c < NC; ++c) {
            const float px = e[c].x * ix, py = e[c].y * iy;
            const float pz = e[c].z * iz, pw = e[c].w * iw;
            psum[c] += (px + py) + (pz + pw);
            float ic = 0.f, tc = 0.f;
            if (t.x == c) { ic += px; tc += 1.f; }
            if (t.y == c) { ic += py; tc += 1.f; }
            if (t.z == c) { ic += pz; tc += 1.f; }
            if (t.w == c) { ic += pw; tc += 1.f; }
            inter[c] += ic;
            tsum[c]  += tc;
        }
    }

    // ---- block reduction: per-class wave shuffle-reduce -> LDS ----
    const int tid = threadIdx.x;
    const int lane = tid & 63;
    const int wv   = tid >> 6;
    #pragma unroll
    for (int c = 0; c < NC; ++c) {
        const float a  = wred(psum[c]);
        const float bb = wred(inter[c]);
        const float cc = wred(tsum[c]);
        if (lane == 0) {
            red[wv][c]        = a;
            red[wv][NC + c]   = bb;
            red[wv][2*NC + c] = cc;
        }
    }
    __syncthreads();

    if (tid < 48) {
        const float v = red[0][tid] + red[1][tid] + red[2][tid] + red[3][tid];
        atomicAdd(&ws[(blockIdx.x & (NBUK - 1)) * 48 + tid], v);
        __threadfence();
    }
    __syncthreads();

    // ---- last-block finalize ----
    if (tid == 0) {
        const int old = atomicAdd((int*)(ws + NBUK * 48), 1);
        isLast = (old == NBLK - 1);
    }
    __syncthreads();
    if (!isLast) return;

    __threadfence();
    if (tid < 48) {
        float s = 0.f;
        #pragma unroll
        for (int k = 0; k < NBUK; ++k)
            s += atomicAdd(&ws[k * 48 + tid], 0.0f);   // device-scope coherent read
        fin[tid] = s;
    }
    __syncthreads();
    if (tid == 0) {
        float acc = 0.f;
        #pragma unroll
        for (int c = 0; c < NC; ++c) {
            const float dice = (2.f * fin[NC + c] + 1.f) / (fin[c] + fin[2*NC + c] + 1.f);
            acc += 1.f - dice;
        }
        out[0] = acc * (1.f / 16.f);
    }
}

extern "C" void kernel_launch(void* const* d_in, const int* in_sizes, int n_in,
                              void* d_out, int out_size, void* d_ws, size_t ws_size,
                              hipStream_t stream) {
    const float* logits  = (const float*)d_in[0];
    const int*   targets = (const int*)d_in[1];
    float* ws  = (float*)d_ws;
    float* out = (float*)d_out;

    hipMemsetAsync(ws, 0, 4096, stream);   // buckets + counter
    dice_main<<<NBLK, NTHR, 0, stream>>>(logits, targets, ws, out);
}

// Round 8
// 55.093 us; speedup vs baseline: 1.0199x; 1.0199x over previous
//
#include <hip/hip_runtime.h>

#define HW_    (512*512)        // 262144 pixels per image
#define NC     16
#define NPIX   (8*HW_)
#define NGRP   (NPIX/4)         // 524288 float4 groups
#define GPB4   (HW_/4)          // 65536 groups per image (2^16)
#define NBLK   512
#define NTHR   256
#define STRIDE (NBLK*NTHR)      // 131072; 4 iterations cover NGRP exactly
#define NBUK   16

// ws layout (floats): [NBUK][48] partials; ws[NBUK*48] = block counter (int)
// stat s: 0..15 = p_sum[c], 16..31 = intersection[c], 32..47 = t_sum[c]

__device__ __forceinline__ float wred(float v) {
    v += __shfl_xor(v, 32, 64);
    v += __shfl_xor(v, 16, 64);
    v += __shfl_xor(v,  8, 64);
    v += __shfl_xor(v,  4, 64);
    v += __shfl_xor(v,  2, 64);
    v += __shfl_xor(v,  1, 64);
    return v;
}

__device__ __forceinline__ void loadg(const float4* __restrict__ lf4,
                                      const int4*   __restrict__ tg4,
                                      int g, float4 (&buf)[NC], int4& t) {
    const int b  = g >> 16;            // g / GPB4
    const int s4 = g & (GPB4 - 1);     // g % GPB4
    const float4* lp = lf4 + (size_t)b * (NC * GPB4) + s4;
    t = tg4[(size_t)b * GPB4 + s4];
    #pragma unroll
    for (int c = 0; c < NC; ++c) buf[c] = lp[(size_t)c * GPB4];
}

__device__ __forceinline__ void computeg(float4 (&e)[NC], const int4 t,
                                         float (&psum)[NC], float (&inter)[NC],
                                         unsigned (&cnt)[NC]) {
    float sx = 0.f, sy = 0.f, sz = 0.f, sw = 0.f;
    #pragma unroll
    for (int c = 0; c < NC; ++c) {
        e[c].x = __expf(e[c].x); e[c].y = __expf(e[c].y);
        e[c].z = __expf(e[c].z); e[c].w = __expf(e[c].w);
        sx += e[c].x; sy += e[c].y; sz += e[c].z; sw += e[c].w;
    }
    const float ix = __builtin_amdgcn_rcpf(sx);
    const float iy = __builtin_amdgcn_rcpf(sy);
    const float iz = __builtin_amdgcn_rcpf(sz);
    const float iw = __builtin_amdgcn_rcpf(sw);
    #pragma unroll
    for (int c = 0; c < NC; ++c) {
        const float px = e[c].x * ix, py = e[c].y * iy;
        const float pz = e[c].z * iz, pw = e[c].w * iw;
        psum[c] += (px + py) + (pz + pw);
        inter[c] += (t.x == c ? px : 0.f) + (t.y == c ? py : 0.f)
                  + (t.z == c ? pz : 0.f) + (t.w == c ? pw : 0.f);
        // wave-uniform counts -> SGPR accumulators (no per-lane reduce needed)
        cnt[c] += (unsigned)__popcll(__ballot(t.x == c))
                + (unsigned)__popcll(__ballot(t.y == c))
                + (unsigned)__popcll(__ballot(t.z == c))
                + (unsigned)__popcll(__ballot(t.w == c));
    }
}

__global__ __launch_bounds__(NTHR, 1) void dice_main(
        const float* __restrict__ logits,
        const int*   __restrict__ targets,
        float*       __restrict__ ws,
        float*       __restrict__ out) {
    __shared__ float red[4][48];
    __shared__ float fin[48];
    __shared__ int   isLast;

    const int tid = threadIdx.x;

    float psum[NC], inter[NC];
    unsigned cnt[NC];
    #pragma unroll
    for (int c = 0; c < NC; ++c) { psum[c] = 0.f; inter[c] = 0.f; cnt[c] = 0u; }

    const float4* __restrict__ lf4 = reinterpret_cast<const float4*>(logits);
    const int4*   __restrict__ tg4 = reinterpret_cast<const int4*>(targets);

    const int g0 = blockIdx.x * NTHR + tid;

    // ---- software-pipelined: compute(iter k) overlaps loads(iter k+1) ----
    float4 A[NC], B[NC];
    int4 tA, tB;
    loadg(lf4, tg4, g0,              A, tA);
    loadg(lf4, tg4, g0 + STRIDE,     B, tB);
    computeg(A, tA, psum, inter, cnt);
    loadg(lf4, tg4, g0 + 2*STRIDE,   A, tA);
    computeg(B, tB, psum, inter, cnt);
    loadg(lf4, tg4, g0 + 3*STRIDE,   B, tB);
    computeg(A, tA, psum, inter, cnt);
    computeg(B, tB, psum, inter, cnt);

    // ---- block reduction: psum/inter via wave shuffle; tsum is wave-uniform ----
    const int lane = tid & 63;
    const int wv   = tid >> 6;
    #pragma unroll
    for (int c = 0; c < NC; ++c) {
        const float a  = wred(psum[c]);
        const float bb = wred(inter[c]);
        if (lane == 0) {
            red[wv][c]        = a;
            red[wv][NC + c]   = bb;
            red[wv][2*NC + c] = (float)cnt[c];   // wave total (ballot-summed)
        }
    }
    __syncthreads();

    if (tid < 48) {
        const float v = red[0][tid] + red[1][tid] + red[2][tid] + red[3][tid];
        atomicAdd(&ws[(blockIdx.x & (NBUK - 1)) * 48 + tid], v);
        __threadfence();
    }
    __syncthreads();

    // ---- last-block finalize ----
    if (tid == 0) {
        const int old = atomicAdd((int*)(ws + NBUK * 48), 1);
        isLast = (old == NBLK - 1);
    }
    __syncthreads();
    if (!isLast) return;

    __threadfence();
    if (tid < 48) {
        float s = 0.f;
        #pragma unroll
        for (int k = 0; k < NBUK; ++k)
            s += atomicAdd(&ws[k * 48 + tid], 0.0f);   // device-scope coherent read
        fin[tid] = s;
    }
    __syncthreads();
    if (tid == 0) {
        float acc = 0.f;
        #pragma unroll
        for (int c = 0; c < NC; ++c) {
            const float dice = (2.f * fin[NC + c] + 1.f) / (fin[c] + fin[2*NC + c] + 1.f);
            acc += 1.f - dice;
        }
        out[0] = acc * (1.f / 16.f);
    }
}

extern "C" void kernel_launch(void* const* d_in, const int* in_sizes, int n_in,
                              void* d_out, int out_size, void* d_ws, size_t ws_size,
                              hipStream_t stream) {
    const float* logits  = (const float*)d_in[0];
    const int*   targets = (const int*)d_in[1];
    float* ws  = (float*)d_ws;
    float* out = (float*)d_out;

    hipMemsetAsync(ws, 0, 4096, stream);   // buckets + counter
    dice_main<<<NBLK, NTHR, 0, stream>>>(logits, targets, ws, out);
}

// Round 9
// 52.481 us; speedup vs baseline: 1.0706x; 1.0498x over previous
//
#include <hip/hip_runtime.h>

#define HW_    (512*512)       // 262144 pixels per image
#define NC     16
#define NBLK   1024            // 1 wave/block; 4 blocks/CU (LDS-limited)
#define NTILE  8               // tiles per block
#define TPX    256             // pixels per tile (= 64 lanes * 4 px)
// block pixel span = NTILE*TPX = 2048; blocks per image = HW_/2048 = 128
#define NBUK   16
#define RSTRIDE (NC*TPX + TPX) // 17*256 floats per LDS buffer (classes + targets)

// ws layout (floats): [NBUK][48] partials; ws[NBUK*48] = block counter (int)

typedef __attribute__((address_space(3))) void       lds_void;
typedef const __attribute__((address_space(1))) void gbl_void;

__device__ __forceinline__ void dma16(const void* g, void* l) {
    // 16 B per lane: global (per-lane addr) -> LDS (uniform base + lane*16)
    __builtin_amdgcn_global_load_lds((gbl_void*)g, (lds_void*)l, 16, 0, 0);
}

__device__ __forceinline__ float wred(float v) {
    v += __shfl_xor(v, 32, 64);
    v += __shfl_xor(v, 16, 64);
    v += __shfl_xor(v,  8, 64);
    v += __shfl_xor(v,  4, 64);
    v += __shfl_xor(v,  2, 64);
    v += __shfl_xor(v,  1, 64);
    return v;
}

__global__ __launch_bounds__(64, 1) void dice_main(
        const float* __restrict__ logits,
        const int*   __restrict__ targets,
        float*       __restrict__ ws,
        float*       __restrict__ out) {
    __shared__ float lbuf[2][RSTRIDE];   // 34816 B, wave-private (1 wave/block)

    const int lane = threadIdx.x;        // 0..63
    const int bid  = blockIdx.x;
    const int b    = bid >> 7;                   // image index (0..7)
    const int boff = (bid & 127) * (NTILE*TPX);  // pixel offset within image

    const float* gl = logits  + (size_t)b * NC * HW_ + boff + lane * 4;
    const int*   gt = targets + (size_t)b * HW_      + boff + lane * 4;

    auto stage = [&](int buf, int t) {
        const float* gsrc = gl + t * TPX;
        float* ldst = &lbuf[buf][0];
        #pragma unroll
        for (int c = 0; c < NC; ++c)
            dma16(gsrc + (size_t)c * HW_, ldst + c * TPX);
        dma16(gt + t * TPX, ldst + NC * TPX);
    };

    float psum[NC], inter[NC];
    unsigned cnt[NC];
    #pragma unroll
    for (int c = 0; c < NC; ++c) { psum[c] = 0.f; inter[c] = 0.f; cnt[c] = 0u; }

    stage(0, 0);
    #pragma unroll 1
    for (int t = 0; t < NTILE; ++t) {
        if (t + 1 < NTILE) {
            stage((t + 1) & 1, t + 1);                       // prefetch next tile
            asm volatile("s_waitcnt vmcnt(17)" ::: "memory"); // current tile done
        } else {
            asm volatile("s_waitcnt vmcnt(0)" ::: "memory");
        }
        const float4* Lf = (const float4*)&lbuf[t & 1][0];
        const int4 tg = ((const int4*)&lbuf[t & 1][NC * TPX])[lane];

        float4 e[NC];
        float sx = 0.f, sy = 0.f, sz = 0.f, sw = 0.f;
        #pragma unroll
        for (int c = 0; c < NC; ++c) {
            const float4 l = Lf[c * (TPX / 4) + lane];       // ds_read_b128
            e[c].x = __expf(l.x); e[c].y = __expf(l.y);
            e[c].z = __expf(l.z); e[c].w = __expf(l.w);
            sx += e[c].x; sy += e[c].y; sz += e[c].z; sw += e[c].w;
        }
        const float ix = __builtin_amdgcn_rcpf(sx);
        const float iy = __builtin_amdgcn_rcpf(sy);
        const float iz = __builtin_amdgcn_rcpf(sz);
        const float iw = __builtin_amdgcn_rcpf(sw);

        #pragma unroll
        for (int c = 0; c < NC; ++c) {
            const float px = e[c].x * ix, py = e[c].y * iy;
            const float pz = e[c].z * iz, pw = e[c].w * iw;
            psum[c] += (px + py) + (pz + pw);
            inter[c] += (tg.x == c ? px : 0.f) + (tg.y == c ? py : 0.f)
                      + (tg.z == c ? pz : 0.f) + (tg.w == c ? pw : 0.f);
            cnt[c] += (unsigned)__popcll(__ballot(tg.x == c))
                    + (unsigned)__popcll(__ballot(tg.y == c))
                    + (unsigned)__popcll(__ballot(tg.z == c))
                    + (unsigned)__popcll(__ballot(tg.w == c));
        }
    }

    // ---- wave totals -> one 48-lane global atomic ----
    #pragma unroll
    for (int c = 0; c < NC; ++c) { psum[c] = wred(psum[c]); inter[c] = wred(inter[c]); }
    float v = 0.f;
    #pragma unroll
    for (int c = 0; c < NC; ++c) {
        if (lane == c)      v = psum[c];
        if (lane == 16 + c) v = inter[c];
        if (lane == 32 + c) v = (float)cnt[c];   // ballot-summed wave total
    }
    if (lane < 48) atomicAdd(&ws[(bid & (NBUK - 1)) * 48 + lane], v);
    __threadfence();

    int old = 0;
    if (lane == 0) old = atomicAdd((int*)(ws + NBUK * 48), 1);
    old = __shfl(old, 0, 64);
    if (old != NBLK - 1) return;

    // ---- last-block finalize (single wave) ----
    __threadfence();
    float s = 0.f;
    if (lane < 48) {
        #pragma unroll
        for (int k = 0; k < NBUK; ++k)
            s += atomicAdd(&ws[k * 48 + lane], 0.0f);   // device-scope coherent read
    }
    ((float*)lbuf)[lane] = s;
    __syncthreads();
    if (lane < NC) {
        const float f0 = ((float*)lbuf)[lane];
        const float f1 = ((float*)lbuf)[16 + lane];
        const float f2 = ((float*)lbuf)[32 + lane];
        float term = 1.f - (2.f * f1 + 1.f) / (f0 + f2 + 1.f);
        term += __shfl_xor(term, 8, 64);
        term += __shfl_xor(term, 4, 64);
        term += __shfl_xor(term, 2, 64);
        term += __shfl_xor(term, 1, 64);
        if (lane == 0) out[0] = term * (1.f / 16.f);
    }
}

extern "C" void kernel_launch(void* const* d_in, const int* in_sizes, int n_in,
                              void* d_out, int out_size, void* d_ws, size_t ws_size,
                              hipStream_t stream) {
    const float* logits  = (const float*)d_in[0];
    const int*   targets = (const int*)d_in[1];
    float* ws  = (float*)d_ws;
    float* out = (float*)d_out;

    hipMemsetAsync(ws, 0, 4096, stream);   // buckets + counter
    dice_main<<<NBLK, 64, 0, stream>>>(logits, targets, ws, out);
}